// Round 1
// baseline (142.294 us; speedup 1.0000x reference)
//
#include <hip/hip_runtime.h>
#include <stdint.h>

typedef __bf16 bf16x8 __attribute__((ext_vector_type(8)));
typedef float  f32x4  __attribute__((ext_vector_type(4)));
typedef uint32_t u32x4 __attribute__((ext_vector_type(4)));

__device__ __forceinline__ uint16_t f2bf(float f) {
    uint32_t u = __builtin_bit_cast(uint32_t, f);
    u += 0x7FFFu + ((u >> 16) & 1u);          // round-to-nearest-even
    return (uint16_t)(u >> 16);
}

// ---------------------------------------------------------------------------
// Kernel 1: Q [b][c 256][i 32][j 32] f32 -> Qt [b][ih 2][j 32][ch 32][il 16][8] bf16
//   where c = ch*8 + t, i = ih*16 + il.  Corr's B-fragment load = 1 KB contiguous.
// ---------------------------------------------------------------------------
__global__ __launch_bounds__(256) void qtrans_kernel(const float* __restrict__ Q,
                                                     uint16_t* __restrict__ Qt) {
    // T[c8 8][i 32][j 33] f32, c8-stride 1064 so bank = 8*c8 + i + j
    __shared__ float T[8 * 1064];
    const int ch = blockIdx.x, b = blockIdx.y;
    const int tid = threadIdx.x;

    const float* src = Q + ((size_t)(b * 256 + ch * 8)) * 1024;
    #pragma unroll
    for (int it = 0; it < 32; ++it) {                  // 8192 f32, coalesced
        int r = tid + it * 256;
        int c8 = r >> 10, rem = r & 1023;
        T[c8 * 1064 + (rem >> 5) * 33 + (rem & 31)] = src[(size_t)c8 * 1024 + rem];
    }
    __syncthreads();

    uint32_t* dst = (uint32_t*)Qt;                     // write bf16 pairs
    #pragma unroll
    for (int it = 0; it < 16; ++it) {                  // 4096 pairs
        int o2 = tid + it * 256;
        int t  = (o2 & 3) * 2;
        int il = (o2 >> 2) & 15;
        int j  = (o2 >> 6) & 31;
        int ih = (o2 >> 11) & 1;
        float v0 = T[t * 1064 + (ih * 16 + il) * 33 + j];
        float v1 = T[(t + 1) * 1064 + (ih * 16 + il) * 33 + j];
        uint32_t pk = (uint32_t)f2bf(v0) | ((uint32_t)f2bf(v1) << 16);
        size_t oi = ((((size_t)(b * 2 + ih) * 32 + j) * 32 + ch) * 16 + il) * 4 + (t >> 1);
        dst[oi] = pk;
    }
}

// ---------------------------------------------------------------------------
// Kernel 2: block=(b,d).  P[x][i] = sum_{j,c} S[b,c,d,x+j-16]*Q[b,c,i,j],
// then epilogue atomically adds P into out[b, y=d-i+16, x].
//
// This revision pipelines the three formerly-serial phases:
//   * staging is split in c-halves: ch 0..15 staged before barrier 1; ch 16..31
//     staged INTERLEAVED with the s=0..3 compute bodies (they only read ch<16);
//     barrier 2 sits right before the first s=4 body.
//   * compute runs s-outer/jj-inner (acc sums over both, order-free), flattened
//     to 32 fully-unrolled bodies with a one-body-ahead register prefetch of
//     the 4 Qt B-fragments; body 0's fragments are issued before barrier 1.
// ---------------------------------------------------------------------------
__global__ __launch_bounds__(256, 4) void corr_kernel(const float* __restrict__ S,
                                                      const uint16_t* __restrict__ Qt,
                                                      float* __restrict__ out) {
    __shared__ __align__(16) char smem[40960];         // 40 KB -> 4 blocks/CU
    uint16_t* S_l = (uint16_t*)smem;                   // [ch][row]: idx = ch*640 + row*8
    float*    Pw  = (float*)smem;                      // overlay: [4][iv 32][x 80]

    const int d = blockIdx.x, b = blockIdx.y;
    const int tid = threadIdx.x, wave = tid >> 6, lane = tid & 63;
    const int l15 = lane & 15, l4 = lane >> 4;

    // ---- zero-fill pad rows 0..15 for all ch (8 KB)
    {
        const u32x4 z = {};
        #pragma unroll
        for (int zi = 0; zi < 2; ++zi) {
            int e = tid + zi * 256;
            int ch = e >> 4, r = e & 15;
            *(u32x4*)&S_l[ch * 640 + r * 8] = z;
        }
    }

    const int sx = lane;
    const float* sp = S + ((size_t)b * 256) * 4096 + (size_t)d * 64 + sx;

    // ---- stage FIRST half of S: ch = k*4 + wave, k=0..3  (ch 0..15, for s=0..3)
    #pragma unroll
    for (int k = 0; k < 4; ++k) {
        const int ch = k * 4 + wave;
        float v[8];
        #pragma unroll
        for (int cc = 0; cc < 8; ++cc)
            v[cc] = sp[(size_t)(ch * 8 + cc) * 4096];          // 256B coalesced
        u32x4 pk;
        #pragma unroll
        for (int q = 0; q < 4; ++q)
            pk[q] = (uint32_t)f2bf(v[2 * q]) | ((uint32_t)f2bf(v[2 * q + 1]) << 16);
        *(u32x4*)&S_l[ch * 640 + (sx + 16) * 8] = pk;          // contiguous 1KB/wave
    }

    // ---- B-fragment base; body (s,jj): p = B0 + jj*16384 + s*512 (uint16 elems)
    //      ih=1: +131072 ; j0b=j0a+16: +65536 ; both: +196608
    const uint16_t* B0 = Qt + (((size_t)b * 2) * 32 + wave) * 4096 + l4 * 128 + l15 * 8;

    // prefetch body 0's B-fragments BEFORE the barrier (independent of LDS)
    bf16x8 Bc0 = *(const bf16x8*)(B0);
    bf16x8 Bc1 = *(const bf16x8*)(B0 + 131072);
    bf16x8 Bc2 = *(const bf16x8*)(B0 + 65536);
    bf16x8 Bc3 = *(const bf16x8*)(B0 + 196608);

    __syncthreads();                                   // ch 0..15 visible

    f32x4 acc[5][2] = {};
    float vs[8];                                       // staging transient (one ch row)

    #pragma unroll
    for (int n = 0; n < 32; ++n) {
        const int s = n >> 2, jj = n & 3;

        if (n == 16) __syncthreads();                  // ch 16..31 visible before s=4

        // ---- SECOND-half staging interleaved into early bodies (ch 16..31).
        // loads at n=0,3,6,9 ; pack+LDS-write two bodies later (latency hidden
        // under the intervening MFMAs). All writes land by n=11 < barrier@16.
        if (n == 0 || n == 3 || n == 6 || n == 9) {
            const int ch = 16 + (n / 3) * 4 + wave;
            #pragma unroll
            for (int cc = 0; cc < 8; ++cc)
                vs[cc] = sp[(size_t)(ch * 8 + cc) * 4096];
        }
        if (n == 2 || n == 5 || n == 8 || n == 11) {
            const int ch = 16 + ((n - 2) / 3) * 4 + wave;
            u32x4 pk;
            #pragma unroll
            for (int q = 0; q < 4; ++q)
                pk[q] = (uint32_t)f2bf(vs[2 * q]) | ((uint32_t)f2bf(vs[2 * q + 1]) << 16);
            *(u32x4*)&S_l[ch * 640 + (sx + 16) * 8] = pk;
        }

        // ---- prefetch NEXT body's B-fragments (hide Qt L2 latency under MFMAs)
        bf16x8 Bn0, Bn1, Bn2, Bn3;
        if (n < 31) {
            const int s2 = (n + 1) >> 2, jj2 = (n + 1) & 3;
            const uint16_t* p = B0 + jj2 * 16384 + s2 * 512;
            Bn0 = *(const bf16x8*)(p);
            Bn1 = *(const bf16x8*)(p + 131072);
            Bn2 = *(const bf16x8*)(p + 65536);
            Bn3 = *(const bf16x8*)(p + 196608);
        }

        // ---- A fragments from LDS (conflict-free b128: 2-way aliasing only)
        const int j0a = wave + jj * 4;                 // 0..15 ; j0b = j0a+16
        const int chb = (s * 4 + l4) * 640;
        bf16x8 A[5];
        #pragma unroll
        for (int t = 0; t < 5; ++t) {
            int rr = j0a + t * 16 + l15;               // <= 94
            rr = (rr < 80) ? rr : 0;                   // OOB -> zero-row
            A[t] = *(const bf16x8*)&S_l[chb + rr * 8];
        }

        // ---- 18 MFMAs on the CURRENT (prefetched) B-fragments
        #pragma unroll
        for (int t = 0; t < 5; ++t) {
            acc[t][0] = __builtin_amdgcn_mfma_f32_16x16x32_bf16(A[t], Bc0, acc[t][0], 0, 0, 0);
            acc[t][1] = __builtin_amdgcn_mfma_f32_16x16x32_bf16(A[t], Bc1, acc[t][1], 0, 0, 0);
        }
        #pragma unroll
        for (int t = 1; t < 5; ++t) {
            acc[t - 1][0] = __builtin_amdgcn_mfma_f32_16x16x32_bf16(A[t], Bc2, acc[t - 1][0], 0, 0, 0);
            acc[t - 1][1] = __builtin_amdgcn_mfma_f32_16x16x32_bf16(A[t], Bc3, acc[t - 1][1], 0, 0, 0);
        }

        if (n < 31) { Bc0 = Bn0; Bc1 = Bn1; Bc2 = Bn2; Bc3 = Bn3; }
    }

    // ---- merge 4 wave-partials in LDS, then atomic-add into out
    __syncthreads();
    {
        float* pw = Pw + wave * 2560;                  // [iv 32][x 80]
        #pragma unroll
        for (int m = 0; m < 5; ++m)
            #pragma unroll
            for (int nn = 0; nn < 2; ++nn)
                *(f32x4*)&pw[(nn * 16 + l15) * 80 + m * 16 + l4 * 4] = acc[m][nn];
    }
    __syncthreads();
    for (int e = tid; e < 65 * 32; e += 256) {
        int x = e % 65, i = e / 65;
        int y = d - i + 16;
        if ((unsigned)y < 65u) {
            float v = Pw[0 * 2560 + i * 80 + x] + Pw[1 * 2560 + i * 80 + x]
                    + Pw[2 * 2560 + i * 80 + x] + Pw[3 * 2560 + i * 80 + x];
            atomicAdd(out + ((size_t)b * 4225 + (size_t)y * 65 + x), v);
        }
    }
}

// ---------------------------------------------------------------------------
// fp32 fallback (only if workspace is too small) — slow but exact
// ---------------------------------------------------------------------------
__global__ __launch_bounds__(256) void naive_kernel(const float* __restrict__ Q,
                                                    const float* __restrict__ S,
                                                    float* __restrict__ out) {
    int gid = blockIdx.x * 256 + threadIdx.x;
    if (gid >= 67600) return;
    int b = gid / 4225, r = gid % 4225, y = r / 65, x = r % 65;
    int jlo = 16 - x; if (jlo < 0) jlo = 0;
    int jhi = 80 - x; if (jhi > 32) jhi = 32;
    float acc = 0.f;
    for (int c = 0; c < 256; ++c) {
        const float* Sb = S + ((size_t)(b * 256 + c)) * 4096;
        const float* Qb = Q + ((size_t)(b * 256 + c)) * 1024;
        for (int i = 0; i < 32; ++i) {
            int dd = y + i - 16;
            if ((unsigned)dd >= 64u) continue;
            const float* Sr = Sb + dd * 64 + (x - 16);
            const float* Qr = Qb + i * 32;
            for (int j = jlo; j < jhi; ++j) acc += Sr[j] * Qr[j];
        }
    }
    out[gid] = acc;
}

extern "C" void kernel_launch(void* const* d_in, const int* in_sizes, int n_in,
                              void* d_out, int out_size, void* d_ws, size_t ws_size,
                              hipStream_t stream) {
    (void)in_sizes; (void)n_in; (void)out_size;
    const float* Q = (const float*)d_in[0];   // [16,256,32,32] f32
    const float* S = (const float*)d_in[1];   // [16,256,64,64] f32
    float* out = (float*)d_out;               // [16,1,65,65] f32

    const size_t QT_BYTES = (size_t)16 * 2 * 32 * 32 * 16 * 8 * 2;  // 8,388,608

    if (ws_size < QT_BYTES) {
        naive_kernel<<<(67600 + 255) / 256, 256, 0, stream>>>(Q, S, out);
        return;
    }
    uint16_t* Qt = (uint16_t*)d_ws;

    hipMemsetAsync(d_out, 0, (size_t)67600 * sizeof(float), stream);
    qtrans_kernel<<<dim3(32, 16), 256, 0, stream>>>(Q, Qt);
    corr_kernel<<<dim3(64, 16), 256, 0, stream>>>(S, Qt, out);
}